// Round 1
// baseline (858.586 us; speedup 1.0000x reference)
//
#include <hip/hip_runtime.h>

// CapsNet dynamic routing, B=256 N=2048 C=10 D_IN=8 D_OUT=16, ROUTING_ITERS=3.
// Strategy: never materialize u_hat (335 MB). Recompute each routing pass from
// u (16 MB) + W (10 MB), both L3-resident. fp32 vector ALU (no fp32 MFMA on CDNA4).
// ws usage: partials 128*256*160 f32 (20 MB) + v0 + v1 (160 KB each) ~= 20.3 MiB.

#define B_SZ  256
#define N_SZ  2048
#define C_SZ  10
#define DIN   8
#define DOUT  16
#define JO    (C_SZ*DOUT)   // 160
#define IC    16            // i's per block
#define NIC   (N_SZ/IC)     // 128 i-chunks

__device__ __forceinline__ void softmax10(float* a) {
    float m = a[0];
#pragma unroll
    for (int j = 1; j < C_SZ; ++j) m = fmaxf(m, a[j]);
    float s = 0.f;
#pragma unroll
    for (int j = 0; j < C_SZ; ++j) { a[j] = __expf(a[j] - m); s += a[j]; }
    float inv = 1.f / s;
#pragma unroll
    for (int j = 0; j < C_SZ; ++j) a[j] *= inv;
}

// mode 0: iter-0 (uniform c, no v needed)
// mode 1: iter-1 (agreement vs va)
// mode 2: iter-2 (agreement vs va+vb; exact since b_ij = uh.v0 + uh.v1 = uh.(v0+v1))
__global__ __launch_bounds__(256, 2)
void caps_phase(const float* __restrict__ u, const float* __restrict__ W,
                const float* __restrict__ va, const float* __restrict__ vb,
                float* __restrict__ s_part, int mode)
{
    // lds[0]: staged v (transposed [jo][b], XOR-swizzled cols)
    // lds[1]: s accumulator (same layout). 2 * 40960 B = 80 KiB -> 2 blocks/CU.
    __shared__ float lds[2][JO*64];
    float* vlds = lds[0];
    float* slds = lds[1];
    const int tid  = threadIdx.x;
    const int lane = tid & 63;
    const int wid  = tid >> 6;
    const int bg   = blockIdx.x & 3;     // which 64-b group
    const int ic   = blockIdx.x >> 2;    // which i-chunk
    const int b    = bg*64 + lane;

    for (int k = tid; k < JO*64; k += 256) slds[k] = 0.f;
    if (mode >= 1) {
        for (int k = tid; k < JO*64; k += 256) {   // coalesced global read
            int jo = k % JO, bb = k / JO;
            float v = va[(bg*64 + bb)*JO + jo];
            if (mode == 2) v += vb[(bg*64 + bb)*JO + jo];
            vlds[jo*64 + (bb ^ (jo & 31))] = v;    // swizzle keeps all patterns conflict-free
        }
    }
    __syncthreads();

    for (int p = 0; p < 2; ++p) {
        // wave-uniform i pair
        const int i0 = __builtin_amdgcn_readfirstlane(ic*IC + wid*4 + p*2);
        const float* up = u + ((size_t)b*N_SZ + i0)*DIN;   // 64 B contiguous per lane
        float u0[8], u1[8];
        {
            float4 x0 = ((const float4*)up)[0];
            float4 x1 = ((const float4*)up)[1];
            float4 x2 = ((const float4*)up)[2];
            float4 x3 = ((const float4*)up)[3];
            u0[0]=x0.x; u0[1]=x0.y; u0[2]=x0.z; u0[3]=x0.w;
            u0[4]=x1.x; u0[5]=x1.y; u0[6]=x1.z; u0[7]=x1.w;
            u1[0]=x2.x; u1[1]=x2.y; u1[2]=x2.z; u1[3]=x2.w;
            u1[4]=x3.x; u1[5]=x3.y; u1[6]=x3.z; u1[7]=x3.w;
        }
        const float* W0 = W + (size_t)i0*(C_SZ*DOUT*DIN);  // wave-uniform -> scalar/broadcast loads
        const float* W1 = W0 + C_SZ*DOUT*DIN;

        float c0[C_SZ], c1[C_SZ];
        if (mode >= 1) {
            // pass 1: agreement logits a[j] = sum_o uh[j,o] * v[j,o]
#pragma unroll
            for (int j = 0; j < C_SZ; ++j) {
                float acc0 = 0.f, acc1 = 0.f;
                for (int oo = 0; oo < DOUT; oo += 4) {
#pragma unroll
                    for (int oq = 0; oq < 4; ++oq) {
                        const int jo = j*DOUT + oo + oq;
                        const float* w0 = W0 + jo*DIN;
                        const float* w1 = W1 + jo*DIN;
                        float uh0 = 0.f, uh1 = 0.f;
#pragma unroll
                        for (int n = 0; n < DIN; ++n) {
                            uh0 = fmaf(w0[n], u0[n], uh0);
                            uh1 = fmaf(w1[n], u1[n], uh1);
                        }
                        float vv = vlds[jo*64 + (lane ^ (jo & 31))];
                        acc0 = fmaf(uh0, vv, acc0);
                        acc1 = fmaf(uh1, vv, acc1);
                    }
                }
                c0[j] = acc0; c1[j] = acc1;
            }
            softmax10(c0);   // fully per-lane, no divergence
            softmax10(c1);
        }
        // pass 2: s[j,o] += c[j] * uh[j,o]  (recompute uh; W rows are L1/sL1-hot)
#pragma unroll
        for (int j = 0; j < C_SZ; ++j) {
            const float w0c = (mode >= 1) ? c0[j] : 1.f;
            const float w1c = (mode >= 1) ? c1[j] : 1.f;
            for (int oo = 0; oo < DOUT; oo += 4) {
#pragma unroll
                for (int oq = 0; oq < 4; ++oq) {
                    const int jo = j*DOUT + oo + oq;
                    const float* w0 = W0 + jo*DIN;
                    const float* w1 = W1 + jo*DIN;
                    float uh0 = 0.f, uh1 = 0.f;
#pragma unroll
                    for (int n = 0; n < DIN; ++n) {
                        uh0 = fmaf(w0[n], u0[n], uh0);
                        uh1 = fmaf(w1[n], u1[n], uh1);
                    }
                    float val = fmaf(w0c, uh0, w1c*uh1);
                    atomicAdd(&slds[jo*64 + (lane ^ (jo & 31))], val);  // ds_add_f32, conflict-free
                }
            }
        }
    }
    __syncthreads();
    // deposit block partial (non-atomic, disjoint slices), coalesced global writes
    float* outp = s_part + ((size_t)ic*B_SZ + bg*64)*JO;
    for (int k = tid; k < JO*64; k += 256) {
        int jo = k % JO, bb = k / JO;
        outp[(size_t)bb*JO + jo] = slds[jo*64 + (bb ^ (jo & 31))];
    }
}

// Sum NIC partials -> s, squash -> v. Optionally emit final outputs.
__global__ __launch_bounds__(256)
void caps_reduce(const float* __restrict__ s_part, float pre_scale,
                 float* __restrict__ v_next, float* __restrict__ out_v,
                 float* __restrict__ out_logit)
{
    const int idx = blockIdx.x*256 + threadIdx.x;   // b*JO + jo, < 40960
    float s = 0.f;
    for (int icc = 0; icc < NIC; ++icc)
        s += s_part[(size_t)icc*(B_SZ*JO) + idx];   // coalesced, stride B*JO
    s *= pre_scale;                                  // 0.1f for iter-0 uniform c
    // squash: 16-lane groups = one (b,j) row (JO % 16 == 0, rows never straddle)
    float n2 = s*s;
    n2 += __shfl_xor(n2, 1, 16);
    n2 += __shfl_xor(n2, 2, 16);
    n2 += __shfl_xor(n2, 4, 16);
    n2 += __shfl_xor(n2, 8, 16);
    float norm  = sqrtf(n2);
    float nc    = fmaxf(norm, 1e-7f);
    float scale = 1.f - 1.f/(1.f + nc*nc);
    float v = scale * (s / nc);
    if (v_next) v_next[idx] = v;
    if (out_v) {
        out_v[idx] = v;
        float q = v*v;
        q += __shfl_xor(q, 1, 16);
        q += __shfl_xor(q, 2, 16);
        q += __shfl_xor(q, 4, 16);
        q += __shfl_xor(q, 8, 16);
        if ((idx & 15) == 0) out_logit[idx >> 4] = sqrtf(q);  // idx>>4 == b*10 + j
    }
}

extern "C" void kernel_launch(void* const* d_in, const int* in_sizes, int n_in,
                              void* d_out, int out_size, void* d_ws, size_t ws_size,
                              hipStream_t stream)
{
    const float* u = (const float*)d_in[0];   // [256,2048,8]
    const float* W = (const float*)d_in[1];   // [2048,10,16,8]
    float* outp   = (float*)d_out;            // v_j [256,10,16] then logits [256,10]
    float* s_part = (float*)d_ws;                          // NIC*B*JO f32
    float* v0 = s_part + (size_t)NIC*B_SZ*JO;
    float* v1 = v0 + B_SZ*JO;
    float* out_v = outp;
    float* out_logit = outp + B_SZ*JO;

    dim3 blk(256), gphase(4*NIC), gred(B_SZ*JO/256);   // 512 blocks / 160 blocks

    // iter 0: c uniform (pre_scale 0.1) -> v0
    caps_phase<<<gphase, blk, 0, stream>>>(u, W, nullptr, nullptr, s_part, 0);
    caps_reduce<<<gred, blk, 0, stream>>>(s_part, 0.1f, v0, nullptr, nullptr);
    // iter 1: b = uh.v0 -> v1
    caps_phase<<<gphase, blk, 0, stream>>>(u, W, v0, nullptr, s_part, 1);
    caps_reduce<<<gred, blk, 0, stream>>>(s_part, 1.0f, v1, nullptr, nullptr);
    // iter 2: b = uh.(v0+v1) -> v2, logits
    caps_phase<<<gphase, blk, 0, stream>>>(u, W, v0, v1, s_part, 2);
    caps_reduce<<<gred, blk, 0, stream>>>(s_part, 1.0f, nullptr, out_v, out_logit);
}